// Round 1
// baseline (12247.328 us; speedup 1.0000x reference)
//
#include <hip/hip_runtime.h>

#define NN 100000
#define EE 400000
#define HH 512

// ---------------- Layer 1: scalar aggregate (x is [N,1]) ----------------
__global__ void scatter_scalar(const float* __restrict__ x,
                               const int* __restrict__ src,
                               const int* __restrict__ dst,
                               float* __restrict__ agg0) {
    int e = blockIdx.x * blockDim.x + threadIdx.x;
    if (e < EE) atomicAdd(&agg0[dst[e]], x[src[e]]);
}

// x1[i][h] = relu(agg0[i]*w_rel[h] + b[h] + x[i]*w_root[h])
__global__ void layer1_expand(const float* __restrict__ x,
                              const float* __restrict__ agg0,
                              const float* __restrict__ w_rel,
                              const float* __restrict__ b,
                              const float* __restrict__ w_root,
                              float* __restrict__ x1) {
    int idx = blockIdx.x * blockDim.x + threadIdx.x;   // over N * (H/4)
    int i = idx >> 7;            // H/4 = 128 quads per row
    if (i >= NN) return;
    int q = (idx & 127) << 2;
    float a = agg0[i], xv = x[i];
    float4 wr = *(const float4*)&w_rel[q];
    float4 bb = *(const float4*)&b[q];
    float4 wt = *(const float4*)&w_root[q];
    float4 o;
    o.x = fmaxf(fmaf(a, wr.x, fmaf(xv, wt.x, bb.x)), 0.f);
    o.y = fmaxf(fmaf(a, wr.y, fmaf(xv, wt.y, bb.y)), 0.f);
    o.z = fmaxf(fmaf(a, wr.z, fmaf(xv, wt.z, bb.z)), 0.f);
    o.w = fmaxf(fmaf(a, wr.w, fmaf(xv, wt.w, bb.w)), 0.f);
    *(float4*)&x1[(size_t)i * HH + q] = o;
}

// ---------------- Scatter: agg[dst] += xp[src], row-wise ----------------
__global__ void scatter_rows(const float* __restrict__ xp,
                             const int* __restrict__ src,
                             const int* __restrict__ dst,
                             float* __restrict__ agg) {
    long long idx = (long long)blockIdx.x * blockDim.x + threadIdx.x; // E * 128 quads
    if (idx >= (long long)EE * 128) return;
    int e = (int)(idx >> 7);
    int q = ((int)idx & 127) << 2;
    int s = src[e], d = dst[e];
    float4 v = *(const float4*)&xp[(size_t)s * HH + q];
    float* p = &agg[(size_t)d * HH + q];
    atomicAdd(p + 0, v.x);
    atomicAdd(p + 1, v.y);
    atomicAdd(p + 2, v.z);
    atomicAdd(p + 3, v.w);
}

// ---------------- Fused GEMM ----------------
// out[i][h] = (relu?)( sum_k agg[i][k]*w_rel[k][h] + sum_k xp[i][k]*w_root[k][h] + b[h] )
//             (+ xp[i][h] if RESID)
// Combined K = 1024: first 512 from (agg, w_rel), second 512 from (xp, w_root).
// BM=BN=64, BK=16, 256 threads, 4x4 microtile per thread.
template<bool RELU, bool RESID>
__global__ __launch_bounds__(256) void gemm_fused(
    const float* __restrict__ agg, const float* __restrict__ xp,
    const float* __restrict__ w_rel, const float* __restrict__ w_root,
    const float* __restrict__ bias, float* __restrict__ out, int M)
{
    __shared__ float As[16][68];   // [k][m], +4 pad keeps float4 alignment
    __shared__ float Bs[16][68];   // [k][n]

    const int row0 = blockIdx.x * 64;
    const int col0 = blockIdx.y * 64;
    const int tid = threadIdx.x;
    const int tr = tid >> 4;       // 0..15
    const int tc = tid & 15;       // 0..15

    float acc[4][4];
    #pragma unroll
    for (int i = 0; i < 4; ++i)
        #pragma unroll
        for (int j = 0; j < 4; ++j) acc[i][j] = 0.f;

    for (int k0 = 0; k0 < 1024; k0 += 16) {
        const float* A = (k0 < 512) ? agg  : xp;
        const float* B = (k0 < 512) ? w_rel : w_root;
        const int kk = k0 & 511;

        // Load A tile: 64 rows x 16 k. thread t -> row t/4, k quad (t%4)*4
        {
            int r  = tid >> 2;
            int c4 = (tid & 3) << 2;
            int row = row0 + r;
            float4 v = make_float4(0.f, 0.f, 0.f, 0.f);
            if (row < M) v = *(const float4*)&A[(size_t)row * HH + kk + c4];
            As[c4 + 0][r] = v.x;
            As[c4 + 1][r] = v.y;
            As[c4 + 2][r] = v.z;
            As[c4 + 3][r] = v.w;
        }
        // Load B tile: 16 k x 64 cols. thread t -> k t/16, col quad (t%16)*4
        {
            int r  = tid >> 4;
            int c4 = (tid & 15) << 2;
            float4 v = *(const float4*)&B[(size_t)(kk + r) * HH + col0 + c4];
            Bs[r][c4 + 0] = v.x;
            Bs[r][c4 + 1] = v.y;
            Bs[r][c4 + 2] = v.z;
            Bs[r][c4 + 3] = v.w;
        }
        __syncthreads();

        #pragma unroll
        for (int k = 0; k < 16; ++k) {
            float4 av = *(const float4*)&As[k][tr << 2];
            float4 bv = *(const float4*)&Bs[k][tc << 2];
            float a[4] = {av.x, av.y, av.z, av.w};
            float b[4] = {bv.x, bv.y, bv.z, bv.w};
            #pragma unroll
            for (int i = 0; i < 4; ++i)
                #pragma unroll
                for (int j = 0; j < 4; ++j)
                    acc[i][j] = fmaf(a[i], b[j], acc[i][j]);
        }
        __syncthreads();
    }

    // Epilogue: bias (+relu) (+residual), float4 stores
    #pragma unroll
    for (int i = 0; i < 4; ++i) {
        int row = row0 + (tr << 2) + i;
        if (row >= M) break;
        int col = col0 + (tc << 2);
        float4 bb = *(const float4*)&bias[col];
        float4 v;
        v.x = acc[i][0] + bb.x;
        v.y = acc[i][1] + bb.y;
        v.z = acc[i][2] + bb.z;
        v.w = acc[i][3] + bb.w;
        if (RELU) {
            v.x = fmaxf(v.x, 0.f); v.y = fmaxf(v.y, 0.f);
            v.z = fmaxf(v.z, 0.f); v.w = fmaxf(v.w, 0.f);
        }
        if (RESID) {
            float4 r = *(const float4*)&xp[(size_t)row * HH + col];
            v.x += r.x; v.y += r.y; v.z += r.z; v.w += r.w;
        }
        *(float4*)&out[(size_t)row * HH + col] = v;
    }
}

extern "C" void kernel_launch(void* const* d_in, const int* in_sizes, int n_in,
                              void* d_out, int out_size, void* d_ws, size_t ws_size,
                              hipStream_t stream) {
    const float* x   = (const float*)d_in[0];
    const int*   ei  = (const int*)d_in[1];
    const int*   src = ei;
    const int*   dst = ei + EE;
    const float* w_rel1  = (const float*)d_in[2];
    const float* b_rel1  = (const float*)d_in[3];
    const float* w_root1 = (const float*)d_in[4];
    const float* w_rel2  = (const float*)d_in[5];
    const float* b_rel2  = (const float*)d_in[6];
    const float* w_root2 = (const float*)d_in[7];
    const float* w_rel3  = (const float*)d_in[8];
    const float* b_rel3  = (const float*)d_in[9];
    const float* w_root3 = (const float*)d_in[10];
    const float* w_rel4  = (const float*)d_in[11];
    const float* b_rel4  = (const float*)d_in[12];
    const float* w_root4 = (const float*)d_in[13];

    const size_t NH = (size_t)NN * HH;
    float* W0 = (float*)d_ws;          // x1, then x3
    float* W1 = W0 + NH;               // agg0 (N floats), then agg per layer
    float* out = (float*)d_out;        // x2, then x4

    dim3 gGemm(1563, 8);               // ceil(100000/64) x (512/64)
    const int nScatQ = 200000;         // E*128 / 256
    const int nExp   = 50000;          // N*128 / 256

    // ---- Layer 1 ----
    hipMemsetAsync(W1, 0, NN * sizeof(float), stream);
    scatter_scalar<<<(EE + 255) / 256, 256, 0, stream>>>(x, src, dst, W1);
    layer1_expand<<<nExp, 256, 0, stream>>>(x, W1, w_rel1, b_rel1, w_root1, W0);

    // ---- Layer 2: x2 = relu(conv(x1)) + x1 -> d_out ----
    hipMemsetAsync(W1, 0, NH * sizeof(float), stream);
    scatter_rows<<<nScatQ, 256, 0, stream>>>(W0, src, dst, W1);
    gemm_fused<true, true><<<gGemm, 256, 0, stream>>>(W1, W0, w_rel2, w_root2, b_rel2, out, NN);

    // ---- Layer 3: x3 = conv(x2) + x2 -> W0 ----
    hipMemsetAsync(W1, 0, NH * sizeof(float), stream);
    scatter_rows<<<nScatQ, 256, 0, stream>>>(out, src, dst, W1);
    gemm_fused<false, true><<<gGemm, 256, 0, stream>>>(W1, out, w_rel3, w_root3, b_rel3, W0, NN);

    // ---- Layer 4: x4 = conv(x3) + x3 -> d_out ----
    hipMemsetAsync(W1, 0, NH * sizeof(float), stream);
    scatter_rows<<<nScatQ, 256, 0, stream>>>(W0, src, dst, W1);
    gemm_fused<false, true><<<gGemm, 256, 0, stream>>>(W1, W0, w_rel4, w_root4, b_rel4, out, NN);
}

// Round 2
// 4867.081 us; speedup vs baseline: 2.5164x; 2.5164x over previous
//
#include <hip/hip_runtime.h>

#define NN 100000
#define EE 400000
#define HH 512
#define NB_SCAN 98   // ceil(NN/1024)

// ================= CSR build =================
__global__ void histo_deg(const int* __restrict__ dst, int* __restrict__ deg) {
    int e = blockIdx.x * blockDim.x + threadIdx.x;
    if (e < EE) atomicAdd(&deg[dst[e]], 1);
}

__global__ void scan_reduce(const int* __restrict__ deg, int* __restrict__ blockSums) {
    __shared__ int s[256];
    int b = blockIdx.x, t = threadIdx.x;
    int base = b * 1024 + t * 4;
    int v = 0;
    #pragma unroll
    for (int j = 0; j < 4; ++j) { int i = base + j; if (i < NN) v += deg[i]; }
    s[t] = v; __syncthreads();
    for (int off = 128; off > 0; off >>= 1) {
        if (t < off) s[t] += s[t + off];
        __syncthreads();
    }
    if (t == 0) blockSums[b] = s[0];
}

__global__ void scan_top(int* __restrict__ blockSums, int* __restrict__ start) {
    __shared__ int s[128];
    int t = threadIdx.x;
    s[t] = (t < NB_SCAN) ? blockSums[t] : 0;
    __syncthreads();
    for (int off = 1; off < 128; off <<= 1) {
        int u = (t >= off) ? s[t - off] : 0;
        __syncthreads();
        s[t] += u;
        __syncthreads();
    }
    if (t < NB_SCAN) blockSums[t] = (t == 0) ? 0 : s[t - 1];  // exclusive
    if (t == 0) start[NN] = EE;
}

__global__ void scan_down(const int* __restrict__ deg, const int* __restrict__ blockSums,
                          int* __restrict__ start, int* __restrict__ cursor) {
    __shared__ int s[256];
    int b = blockIdx.x, t = threadIdx.x;
    int base = b * 1024 + t * 4;
    int v[4]; int sum = 0;
    #pragma unroll
    for (int j = 0; j < 4; ++j) {
        int i = base + j;
        v[j] = (i < NN) ? deg[i] : 0;
        sum += v[j];
    }
    s[t] = sum; __syncthreads();
    for (int off = 1; off < 256; off <<= 1) {
        int u = (t >= off) ? s[t - off] : 0;
        __syncthreads();
        s[t] += u;
        __syncthreads();
    }
    int excl = blockSums[b] + ((t == 0) ? 0 : s[t - 1]);
    #pragma unroll
    for (int j = 0; j < 4; ++j) {
        int i = base + j;
        if (i < NN) { start[i] = excl; cursor[i] = excl; excl += v[j]; }
    }
}

__global__ void csr_fill(const int* __restrict__ src, const int* __restrict__ dst,
                         int* __restrict__ cursor, int* __restrict__ eidx) {
    int e = blockIdx.x * blockDim.x + threadIdx.x;
    if (e < EE) {
        int p = atomicAdd(&cursor[dst[e]], 1);
        eidx[p] = src[e];
    }
}

// ================= Aggregation (gather) =================
// One wave per node; lane l owns columns [l*8, l*8+8).
__global__ __launch_bounds__(256) void gather_rows(
    const float* __restrict__ xp, const int* __restrict__ start,
    const int* __restrict__ eidx, float* __restrict__ agg)
{
    int node = blockIdx.x * 4 + (threadIdx.x >> 6);
    if (node >= NN) return;
    int c0 = (threadIdx.x & 63) << 3;
    float4 a0 = make_float4(0.f, 0.f, 0.f, 0.f);
    float4 a1 = make_float4(0.f, 0.f, 0.f, 0.f);
    int e0 = start[node], e1 = start[node + 1];
    for (int e = e0; e < e1; ++e) {
        const float* row = &xp[(size_t)eidx[e] * HH + c0];
        float4 v0 = *(const float4*)row;
        float4 v1 = *(const float4*)(row + 4);
        a0.x += v0.x; a0.y += v0.y; a0.z += v0.z; a0.w += v0.w;
        a1.x += v1.x; a1.y += v1.y; a1.z += v1.z; a1.w += v1.w;
    }
    float* o = &agg[(size_t)node * HH + c0];
    *(float4*)o = a0;
    *(float4*)(o + 4) = a1;
}

// Layer-1 scalar aggregate via CSR
__global__ void gather_scalar(const float* __restrict__ x, const int* __restrict__ start,
                              const int* __restrict__ eidx, float* __restrict__ agg0) {
    int i = blockIdx.x * blockDim.x + threadIdx.x;
    if (i >= NN) return;
    float s = 0.f;
    int e1 = start[i + 1];
    for (int e = start[i]; e < e1; ++e) s += x[eidx[e]];
    agg0[i] = s;
}

// x1[i][h] = relu(agg0[i]*w_rel[h] + b[h] + x[i]*w_root[h])
__global__ void layer1_expand(const float* __restrict__ x,
                              const float* __restrict__ agg0,
                              const float* __restrict__ w_rel,
                              const float* __restrict__ b,
                              const float* __restrict__ w_root,
                              float* __restrict__ x1) {
    int idx = blockIdx.x * blockDim.x + threadIdx.x;
    int i = idx >> 7;
    if (i >= NN) return;
    int q = (idx & 127) << 2;
    float a = agg0[i], xv = x[i];
    float4 wr = *(const float4*)&w_rel[q];
    float4 bb = *(const float4*)&b[q];
    float4 wt = *(const float4*)&w_root[q];
    float4 o;
    o.x = fmaxf(fmaf(a, wr.x, fmaf(xv, wt.x, bb.x)), 0.f);
    o.y = fmaxf(fmaf(a, wr.y, fmaf(xv, wt.y, bb.y)), 0.f);
    o.z = fmaxf(fmaf(a, wr.z, fmaf(xv, wt.z, bb.z)), 0.f);
    o.w = fmaxf(fmaf(a, wr.w, fmaf(xv, wt.w, bb.w)), 0.f);
    *(float4*)&x1[(size_t)i * HH + q] = o;
}

// ================= Fused GEMM =================
// out = (relu?)(agg@w_rel + xp@w_root + b) (+ xp if RESID); combined K=1024
template<bool RELU, bool RESID>
__global__ __launch_bounds__(256) void gemm_fused(
    const float* __restrict__ agg, const float* __restrict__ xp,
    const float* __restrict__ w_rel, const float* __restrict__ w_root,
    const float* __restrict__ bias, float* __restrict__ out, int M)
{
    __shared__ float As[16][68];
    __shared__ float Bs[16][68];

    const int row0 = blockIdx.x * 64;
    const int col0 = blockIdx.y * 64;
    const int tid = threadIdx.x;
    const int tr = tid >> 4;
    const int tc = tid & 15;

    float acc[4][4];
    #pragma unroll
    for (int i = 0; i < 4; ++i)
        #pragma unroll
        for (int j = 0; j < 4; ++j) acc[i][j] = 0.f;

    for (int k0 = 0; k0 < 1024; k0 += 16) {
        const float* A = (k0 < 512) ? agg  : xp;
        const float* B = (k0 < 512) ? w_rel : w_root;
        const int kk = k0 & 511;
        {
            int r  = tid >> 2;
            int c4 = (tid & 3) << 2;
            int row = row0 + r;
            float4 v = make_float4(0.f, 0.f, 0.f, 0.f);
            if (row < M) v = *(const float4*)&A[(size_t)row * HH + kk + c4];
            As[c4 + 0][r] = v.x;
            As[c4 + 1][r] = v.y;
            As[c4 + 2][r] = v.z;
            As[c4 + 3][r] = v.w;
        }
        {
            int r  = tid >> 4;
            int c4 = (tid & 15) << 2;
            float4 v = *(const float4*)&B[(size_t)(kk + r) * HH + col0 + c4];
            Bs[r][c4 + 0] = v.x;
            Bs[r][c4 + 1] = v.y;
            Bs[r][c4 + 2] = v.z;
            Bs[r][c4 + 3] = v.w;
        }
        __syncthreads();

        #pragma unroll
        for (int k = 0; k < 16; ++k) {
            float4 av = *(const float4*)&As[k][tr << 2];
            float4 bv = *(const float4*)&Bs[k][tc << 2];
            float a[4] = {av.x, av.y, av.z, av.w};
            float b[4] = {bv.x, bv.y, bv.z, bv.w};
            #pragma unroll
            for (int i = 0; i < 4; ++i)
                #pragma unroll
                for (int j = 0; j < 4; ++j)
                    acc[i][j] = fmaf(a[i], b[j], acc[i][j]);
        }
        __syncthreads();
    }

    #pragma unroll
    for (int i = 0; i < 4; ++i) {
        int row = row0 + (tr << 2) + i;
        if (row >= M) break;
        int col = col0 + (tc << 2);
        float4 bb = *(const float4*)&bias[col];
        float4 v;
        v.x = acc[i][0] + bb.x;
        v.y = acc[i][1] + bb.y;
        v.z = acc[i][2] + bb.z;
        v.w = acc[i][3] + bb.w;
        if (RELU) {
            v.x = fmaxf(v.x, 0.f); v.y = fmaxf(v.y, 0.f);
            v.z = fmaxf(v.z, 0.f); v.w = fmaxf(v.w, 0.f);
        }
        if (RESID) {
            float4 r = *(const float4*)&xp[(size_t)row * HH + col];
            v.x += r.x; v.y += r.y; v.z += r.z; v.w += r.w;
        }
        *(float4*)&out[(size_t)row * HH + col] = v;
    }
}

extern "C" void kernel_launch(void* const* d_in, const int* in_sizes, int n_in,
                              void* d_out, int out_size, void* d_ws, size_t ws_size,
                              hipStream_t stream) {
    const float* x   = (const float*)d_in[0];
    const int*   ei  = (const int*)d_in[1];
    const int*   src = ei;
    const int*   dst = ei + EE;
    const float* w_rel1  = (const float*)d_in[2];
    const float* b_rel1  = (const float*)d_in[3];
    const float* w_root1 = (const float*)d_in[4];
    const float* w_rel2  = (const float*)d_in[5];
    const float* b_rel2  = (const float*)d_in[6];
    const float* w_root2 = (const float*)d_in[7];
    const float* w_rel3  = (const float*)d_in[8];
    const float* b_rel3  = (const float*)d_in[9];
    const float* w_root3 = (const float*)d_in[10];
    const float* w_rel4  = (const float*)d_in[11];
    const float* b_rel4  = (const float*)d_in[12];
    const float* w_root4 = (const float*)d_in[13];

    const size_t NH = (size_t)NN * HH;
    float* W0  = (float*)d_ws;              // x1, then x3
    float* W1  = W0 + NH;                   // agg buffer (also agg0 scalar)
    int*   csr = (int*)(W1 + NH);
    int*   deg       = csr;                 // NN
    int*   start     = csr + NN;            // NN+1
    int*   cursor    = start + NN + 1;      // NN
    int*   eidx      = cursor + NN;         // EE
    int*   blockSums = eidx + EE;           // 128
    float* out = (float*)d_out;

    dim3 gGemm(1563, 8);

    // ---- CSR build ----
    hipMemsetAsync(deg, 0, NN * sizeof(int), stream);
    histo_deg<<<(EE + 255) / 256, 256, 0, stream>>>(dst, deg);
    scan_reduce<<<NB_SCAN, 256, 0, stream>>>(deg, blockSums);
    scan_top<<<1, 128, 0, stream>>>(blockSums, start);
    scan_down<<<NB_SCAN, 256, 0, stream>>>(deg, blockSums, start, cursor);
    csr_fill<<<(EE + 255) / 256, 256, 0, stream>>>(src, dst, cursor, eidx);

    // ---- Layer 1 ----
    gather_scalar<<<(NN + 255) / 256, 256, 0, stream>>>(x, start, eidx, W1);
    layer1_expand<<<50000, 256, 0, stream>>>(x, W1, w_rel1, b_rel1, w_root1, W0);

    // ---- Layer 2: x2 = relu(conv(x1)) + x1 -> d_out ----
    gather_rows<<<25000, 256, 0, stream>>>(W0, start, eidx, W1);
    gemm_fused<true, true><<<gGemm, 256, 0, stream>>>(W1, W0, w_rel2, w_root2, b_rel2, out, NN);

    // ---- Layer 3: x3 = conv(x2) + x2 -> W0 ----
    gather_rows<<<25000, 256, 0, stream>>>(out, start, eidx, W1);
    gemm_fused<false, true><<<gGemm, 256, 0, stream>>>(W1, out, w_rel3, w_root3, b_rel3, W0, NN);

    // ---- Layer 4: x4 = conv(x3) + x3 -> d_out ----
    gather_rows<<<25000, 256, 0, stream>>>(W0, start, eidx, W1);
    gemm_fused<false, true><<<gGemm, 256, 0, stream>>>(W1, W0, w_rel4, w_root4, b_rel4, out, NN);
}

// Round 3
// 1177.709 us; speedup vs baseline: 10.3993x; 4.1327x over previous
//
#include <hip/hip_runtime.h>

#define NN 100000
#define EE 400000
#define HH 512
#define NB_SCAN 98   // ceil(NN/1024)

typedef __attribute__((ext_vector_type(8))) short short8;
typedef __attribute__((ext_vector_type(8))) unsigned short ushort8;
typedef __attribute__((ext_vector_type(4))) float f32x4;

__device__ inline unsigned short f2b(float f) {   // f32 -> bf16 RNE
    unsigned int u = __float_as_uint(f);
    return (unsigned short)((u + 0x7fffu + ((u >> 16) & 1u)) >> 16);
}
__device__ inline float b2f(unsigned short b) {
    return __uint_as_float(((unsigned int)b) << 16);
}

// ================= CSR build =================
__global__ void histo_deg(const int* __restrict__ dst, int* __restrict__ deg) {
    int e = blockIdx.x * blockDim.x + threadIdx.x;
    if (e < EE) atomicAdd(&deg[dst[e]], 1);
}

__global__ void scan_reduce(const int* __restrict__ deg, int* __restrict__ blockSums) {
    __shared__ int s[256];
    int b = blockIdx.x, t = threadIdx.x;
    int base = b * 1024 + t * 4;
    int v = 0;
    #pragma unroll
    for (int j = 0; j < 4; ++j) { int i = base + j; if (i < NN) v += deg[i]; }
    s[t] = v; __syncthreads();
    for (int off = 128; off > 0; off >>= 1) {
        if (t < off) s[t] += s[t + off];
        __syncthreads();
    }
    if (t == 0) blockSums[b] = s[0];
}

__global__ void scan_top(int* __restrict__ blockSums, int* __restrict__ start) {
    __shared__ int s[128];
    int t = threadIdx.x;
    s[t] = (t < NB_SCAN) ? blockSums[t] : 0;
    __syncthreads();
    for (int off = 1; off < 128; off <<= 1) {
        int u = (t >= off) ? s[t - off] : 0;
        __syncthreads();
        s[t] += u;
        __syncthreads();
    }
    if (t < NB_SCAN) blockSums[t] = (t == 0) ? 0 : s[t - 1];  // exclusive
    if (t == 0) start[NN] = EE;
}

__global__ void scan_down(const int* __restrict__ deg, const int* __restrict__ blockSums,
                          int* __restrict__ start, int* __restrict__ cursor) {
    __shared__ int s[256];
    int b = blockIdx.x, t = threadIdx.x;
    int base = b * 1024 + t * 4;
    int v[4]; int sum = 0;
    #pragma unroll
    for (int j = 0; j < 4; ++j) {
        int i = base + j;
        v[j] = (i < NN) ? deg[i] : 0;
        sum += v[j];
    }
    s[t] = sum; __syncthreads();
    for (int off = 1; off < 256; off <<= 1) {
        int u = (t >= off) ? s[t - off] : 0;
        __syncthreads();
        s[t] += u;
        __syncthreads();
    }
    int excl = blockSums[b] + ((t == 0) ? 0 : s[t - 1]);
    #pragma unroll
    for (int j = 0; j < 4; ++j) {
        int i = base + j;
        if (i < NN) { start[i] = excl; cursor[i] = excl; excl += v[j]; }
    }
}

__global__ void csr_fill(const int* __restrict__ src, const int* __restrict__ dst,
                         int* __restrict__ cursor, int* __restrict__ eidx) {
    int e = blockIdx.x * blockDim.x + threadIdx.x;
    if (e < EE) {
        int p = atomicAdd(&cursor[dst[e]], 1);
        eidx[p] = src[e];
    }
}

// ================= Weight transpose + bf16 convert =================
// wt[n][k] = bf16(w[k][n]); one-time, tiny (512x512)
__global__ void w_transpose(const float* __restrict__ w, unsigned short* __restrict__ wt) {
    int idx = blockIdx.x * 256 + threadIdx.x;  // n*512 + k, k fastest
    int n = idx >> 9, k = idx & 511;
    wt[idx] = f2b(w[(size_t)k * HH + n]);
}

// ================= f32 -> bf16 convert (8 elems/thread) =================
__global__ void f32_to_bf16(const float* __restrict__ in, unsigned short* __restrict__ out) {
    size_t i8 = ((size_t)blockIdx.x * 256 + threadIdx.x) * 8;
    float4 v0 = *(const float4*)(in + i8);
    float4 v1 = *(const float4*)(in + i8 + 4);
    ushort8 o;
    o[0] = f2b(v0.x); o[1] = f2b(v0.y); o[2] = f2b(v0.z); o[3] = f2b(v0.w);
    o[4] = f2b(v1.x); o[5] = f2b(v1.y); o[6] = f2b(v1.z); o[7] = f2b(v1.w);
    *(ushort8*)(out + i8) = o;
}

// ================= Aggregation: bf16 gather, one wave per node =================
__global__ __launch_bounds__(256) void gather_rows_b(
    const unsigned short* __restrict__ xb, const int* __restrict__ start,
    const int* __restrict__ eidx, unsigned short* __restrict__ agg)
{
    int node = blockIdx.x * 4 + (threadIdx.x >> 6);
    if (node >= NN) return;
    int c0 = (threadIdx.x & 63) << 3;   // 8 bf16 per lane
    float a[8] = {0.f,0.f,0.f,0.f,0.f,0.f,0.f,0.f};
    int e1 = start[node + 1];
    for (int e = start[node]; e < e1; ++e) {
        ushort8 v = *(const ushort8*)(xb + (size_t)eidx[e] * HH + c0);
        #pragma unroll
        for (int j = 0; j < 8; ++j) a[j] += b2f(v[j]);
    }
    ushort8 o;
    #pragma unroll
    for (int j = 0; j < 8; ++j) o[j] = f2b(a[j]);
    *(ushort8*)(agg + (size_t)node * HH + c0) = o;
}

// Layer-1 scalar aggregate via CSR
__global__ void gather_scalar(const float* __restrict__ x, const int* __restrict__ start,
                              const int* __restrict__ eidx, float* __restrict__ agg0) {
    int i = blockIdx.x * blockDim.x + threadIdx.x;
    if (i >= NN) return;
    float s = 0.f;
    int e1 = start[i + 1];
    for (int e = start[i]; e < e1; ++e) s += x[eidx[e]];
    agg0[i] = s;
}

// x1[i][h] = relu(agg0[i]*w_rel[h] + b[h] + x[i]*w_root[h]); writes f32 + bf16
__global__ void layer1_expand(const float* __restrict__ x,
                              const float* __restrict__ agg0,
                              const float* __restrict__ w_rel,
                              const float* __restrict__ b,
                              const float* __restrict__ w_root,
                              float* __restrict__ x1,
                              unsigned short* __restrict__ x1b) {
    int idx = blockIdx.x * blockDim.x + threadIdx.x;
    int i = idx >> 7;
    if (i >= NN) return;
    int q = (idx & 127) << 2;
    float a = agg0[i], xv = x[i];
    float4 wr = *(const float4*)&w_rel[q];
    float4 bb = *(const float4*)&b[q];
    float4 wt = *(const float4*)&w_root[q];
    float4 o;
    o.x = fmaxf(fmaf(a, wr.x, fmaf(xv, wt.x, bb.x)), 0.f);
    o.y = fmaxf(fmaf(a, wr.y, fmaf(xv, wt.y, bb.y)), 0.f);
    o.z = fmaxf(fmaf(a, wr.z, fmaf(xv, wt.z, bb.z)), 0.f);
    o.w = fmaxf(fmaf(a, wr.w, fmaf(xv, wt.w, bb.w)), 0.f);
    *(float4*)&x1[(size_t)i * HH + q] = o;
    ushort4 ob = { f2b(o.x), f2b(o.y), f2b(o.z), f2b(o.w) };
    *(ushort4*)&x1b[(size_t)i * HH + q] = ob;
}

// ================= MFMA GEMM =================
// out[i][h] = (relu?)(sum_k AB[i][k]*WrT[h][k] + sum_k XB[i][k]*WoT[h][k] + bias[h]) + resid[i][h]
// A operand: combined K=1024 ([AB | XB]); B operand: transposed bf16 weights [n][k].
// 128x128 tile, BK=32, 4 waves (each 64x64), mfma_f32_16x16x32_bf16.
__device__ inline void gload16(const void* g, void* l) {
    __builtin_amdgcn_global_load_lds(
        (const __attribute__((address_space(1))) unsigned int*)g,
        (__attribute__((address_space(3))) unsigned int*)l,
        16, 0, 0);
}

template<bool RELU>
__global__ __launch_bounds__(256, 2) void gemm_mfma(
    const unsigned short* __restrict__ AB, const unsigned short* __restrict__ XB,
    const unsigned short* __restrict__ WrT, const unsigned short* __restrict__ WoT,
    const float* __restrict__ bias, const float* __restrict__ resid,
    float* __restrict__ out)
{
    __shared__ unsigned short As[128 * 32];  // [row][k]
    __shared__ unsigned short Bs[128 * 32];  // [col][k]
    const int tid  = threadIdx.x;
    const int wave = tid >> 6, lane = tid & 63;
    const int col0 = blockIdx.x * 128;       // n-tile fastest -> A panel L2 reuse
    const int row0 = blockIdx.y * 128;
    const int wr = wave >> 1, wc = wave & 1; // wave's 64x64 quadrant
    const int l16 = lane & 15, lq = lane >> 4;
    const int sRow = lane >> 2;              // staging: row within 16-row chunk
    const int sCol = (lane & 3) << 3;        // staging: k offset (8 bf16 = 16B)

    f32x4 acc[4][4];
    #pragma unroll
    for (int m = 0; m < 4; ++m)
        #pragma unroll
        for (int n = 0; n < 4; ++n)
            acc[m][n] = (f32x4){0.f, 0.f, 0.f, 0.f};

    for (int k0 = 0; k0 < 1024; k0 += 32) {
        const unsigned short* Ap = (k0 < 512) ? AB  : XB;
        const unsigned short* Wp = (k0 < 512) ? WrT : WoT;
        const int kk = k0 & 511;
        #pragma unroll
        for (int i = 0; i < 2; ++i) {
            int chunk = wave * 2 + i;
            int grow = row0 + chunk * 16 + sRow;
            if (grow >= NN) grow = NN - 1;               // clamp: valid reads, stores guarded
            gload16(Ap + (size_t)grow * HH + kk + sCol, As + chunk * 512);
            int gcol = col0 + chunk * 16 + sRow;
            gload16(Wp + (size_t)gcol * HH + kk + sCol, Bs + chunk * 512);
        }
        __syncthreads();

        short8 af[4], bf[4];
        #pragma unroll
        for (int m = 0; m < 4; ++m)
            af[m] = *(const short8*)(As + (wr * 64 + m * 16 + l16) * 32 + lq * 8);
        #pragma unroll
        for (int n = 0; n < 4; ++n)
            bf[n] = *(const short8*)(Bs + (wc * 64 + n * 16 + l16) * 32 + lq * 8);
        #pragma unroll
        for (int m = 0; m < 4; ++m)
            #pragma unroll
            for (int n = 0; n < 4; ++n)
                acc[m][n] = __builtin_amdgcn_mfma_f32_16x16x32_bf16(af[m], bf[n], acc[m][n], 0, 0, 0);
        __syncthreads();
    }

    // Epilogue: + bias (+relu) + resid(f32), guarded f32 stores
    #pragma unroll
    for (int m = 0; m < 4; ++m) {
        #pragma unroll
        for (int j = 0; j < 4; ++j) {
            int row = row0 + wr * 64 + m * 16 + lq * 4 + j;
            if (row >= NN) continue;
            #pragma unroll
            for (int n = 0; n < 4; ++n) {
                int col = col0 + wc * 64 + n * 16 + l16;
                float v = acc[m][n][j] + bias[col];
                if (RELU) v = fmaxf(v, 0.f);
                v += resid[(size_t)row * HH + col];
                out[(size_t)row * HH + col] = v;
            }
        }
    }
}

extern "C" void kernel_launch(void* const* d_in, const int* in_sizes, int n_in,
                              void* d_out, int out_size, void* d_ws, size_t ws_size,
                              hipStream_t stream) {
    const float* x   = (const float*)d_in[0];
    const int*   ei  = (const int*)d_in[1];
    const int*   src = ei;
    const int*   dst = ei + EE;
    const float* w_rel1  = (const float*)d_in[2];
    const float* b_rel1  = (const float*)d_in[3];
    const float* w_root1 = (const float*)d_in[4];
    const float* w_rel2  = (const float*)d_in[5];
    const float* b_rel2  = (const float*)d_in[6];
    const float* w_root2 = (const float*)d_in[7];
    const float* w_rel3  = (const float*)d_in[8];
    const float* b_rel3  = (const float*)d_in[9];
    const float* w_root3 = (const float*)d_in[10];
    const float* w_rel4  = (const float*)d_in[11];
    const float* b_rel4  = (const float*)d_in[12];
    const float* w_root4 = (const float*)d_in[13];

    const size_t NH = (size_t)NN * HH;
    float*          W0  = (float*)d_ws;                 // x1 / x3 (f32)
    unsigned short* XB  = (unsigned short*)(W0 + NH);   // x bf16
    unsigned short* AGB = XB + NH;                      // agg bf16
    unsigned short* WT  = AGB + NH;                     // 6 transposed bf16 weights
    float*          agg0 = (float*)(WT + 6 * 512 * 512);
    int*            csr  = (int*)(agg0 + NN);
    int* deg       = csr;
    int* start     = csr + NN;
    int* cursor    = start + NN + 1;
    int* eidx      = cursor + NN;
    int* blockSums = eidx + EE;
    float* out = (float*)d_out;

    unsigned short* WrT2 = WT;
    unsigned short* WoT2 = WT + 1 * 262144;
    unsigned short* WrT3 = WT + 2 * 262144;
    unsigned short* WoT3 = WT + 3 * 262144;
    unsigned short* WrT4 = WT + 4 * 262144;
    unsigned short* WoT4 = WT + 5 * 262144;

    dim3 gGemm(4, 782);      // x = n-tile (fast), y = m-tile
    const int nConv = 25000; // NH/8/256

    // ---- CSR build ----
    hipMemsetAsync(deg, 0, NN * sizeof(int), stream);
    histo_deg<<<(EE + 255) / 256, 256, 0, stream>>>(dst, deg);
    scan_reduce<<<NB_SCAN, 256, 0, stream>>>(deg, blockSums);
    scan_top<<<1, 128, 0, stream>>>(blockSums, start);
    scan_down<<<NB_SCAN, 256, 0, stream>>>(deg, blockSums, start, cursor);
    csr_fill<<<(EE + 255) / 256, 256, 0, stream>>>(src, dst, cursor, eidx);

    // ---- Weights -> transposed bf16 ----
    w_transpose<<<1024, 256, 0, stream>>>(w_rel2,  WrT2);
    w_transpose<<<1024, 256, 0, stream>>>(w_root2, WoT2);
    w_transpose<<<1024, 256, 0, stream>>>(w_rel3,  WrT3);
    w_transpose<<<1024, 256, 0, stream>>>(w_root3, WoT3);
    w_transpose<<<1024, 256, 0, stream>>>(w_rel4,  WrT4);
    w_transpose<<<1024, 256, 0, stream>>>(w_root4, WoT4);

    // ---- Layer 1: x1 -> W0 (f32) + XB (bf16) ----
    gather_scalar<<<(NN + 255) / 256, 256, 0, stream>>>(x, start, eidx, agg0);
    layer1_expand<<<50000, 256, 0, stream>>>(x, agg0, w_rel1, b_rel1, w_root1, W0, XB);

    // ---- Layer 2: x2 = relu(conv(x1)) + x1 -> d_out ----
    gather_rows_b<<<25000, 256, 0, stream>>>(XB, start, eidx, AGB);
    gemm_mfma<true><<<gGemm, 256, 0, stream>>>(AGB, XB, WrT2, WoT2, b_rel2, W0, out);

    // ---- Layer 3: x3 = conv(x2) + x2 -> W0 ----
    f32_to_bf16<<<nConv, 256, 0, stream>>>(out, XB);
    gather_rows_b<<<25000, 256, 0, stream>>>(XB, start, eidx, AGB);
    gemm_mfma<false><<<gGemm, 256, 0, stream>>>(AGB, XB, WrT3, WoT3, b_rel3, out, W0);

    // ---- Layer 4: x4 = conv(x3) + x3 -> d_out ----
    f32_to_bf16<<<nConv, 256, 0, stream>>>(W0, XB);
    gather_rows_b<<<25000, 256, 0, stream>>>(XB, start, eidx, AGB);
    gemm_mfma<false><<<gGemm, 256, 0, stream>>>(AGB, XB, WrT4, WoT4, b_rel4, W0, out);
}

// Round 4
// 1129.505 us; speedup vs baseline: 10.8431x; 1.0427x over previous
//
#include <hip/hip_runtime.h>

#define NN 100000
#define EE 400000
#define HH 512
#define NB_SCAN 98   // ceil(NN/1024)

typedef __attribute__((ext_vector_type(8))) short short8;
typedef __attribute__((ext_vector_type(8))) unsigned short ushort8;
typedef __attribute__((ext_vector_type(4))) float f32x4;

__device__ inline unsigned short f2b(float f) {   // f32 -> bf16 RNE
    unsigned int u = __float_as_uint(f);
    return (unsigned short)((u + 0x7fffu + ((u >> 16) & 1u)) >> 16);
}
__device__ inline float b2f(unsigned short b) {
    return __uint_as_float(((unsigned int)b) << 16);
}

// ================= CSR build =================
__global__ void histo_deg(const int* __restrict__ dst, int* __restrict__ deg) {
    int e = blockIdx.x * blockDim.x + threadIdx.x;
    if (e < EE) atomicAdd(&deg[dst[e]], 1);
}

__global__ void scan_reduce(const int* __restrict__ deg, int* __restrict__ blockSums) {
    __shared__ int s[256];
    int b = blockIdx.x, t = threadIdx.x;
    int base = b * 1024 + t * 4;
    int v = 0;
    #pragma unroll
    for (int j = 0; j < 4; ++j) { int i = base + j; if (i < NN) v += deg[i]; }
    s[t] = v; __syncthreads();
    for (int off = 128; off > 0; off >>= 1) {
        if (t < off) s[t] += s[t + off];
        __syncthreads();
    }
    if (t == 0) blockSums[b] = s[0];
}

__global__ void scan_top(int* __restrict__ blockSums, int* __restrict__ start) {
    __shared__ int s[128];
    int t = threadIdx.x;
    s[t] = (t < NB_SCAN) ? blockSums[t] : 0;
    __syncthreads();
    for (int off = 1; off < 128; off <<= 1) {
        int u = (t >= off) ? s[t - off] : 0;
        __syncthreads();
        s[t] += u;
        __syncthreads();
    }
    if (t < NB_SCAN) blockSums[t] = (t == 0) ? 0 : s[t - 1];  // exclusive
    if (t == 0) start[NN] = EE;
}

__global__ void scan_down(const int* __restrict__ deg, const int* __restrict__ blockSums,
                          int* __restrict__ start, int* __restrict__ cursor) {
    __shared__ int s[256];
    int b = blockIdx.x, t = threadIdx.x;
    int base = b * 1024 + t * 4;
    int v[4]; int sum = 0;
    #pragma unroll
    for (int j = 0; j < 4; ++j) {
        int i = base + j;
        v[j] = (i < NN) ? deg[i] : 0;
        sum += v[j];
    }
    s[t] = sum; __syncthreads();
    for (int off = 1; off < 256; off <<= 1) {
        int u = (t >= off) ? s[t - off] : 0;
        __syncthreads();
        s[t] += u;
        __syncthreads();
    }
    int excl = blockSums[b] + ((t == 0) ? 0 : s[t - 1]);
    #pragma unroll
    for (int j = 0; j < 4; ++j) {
        int i = base + j;
        if (i < NN) { start[i] = excl; cursor[i] = excl; excl += v[j]; }
    }
}

__global__ void csr_fill(const int* __restrict__ src, const int* __restrict__ dst,
                         int* __restrict__ cursor, int* __restrict__ eidx) {
    int e = blockIdx.x * blockDim.x + threadIdx.x;
    if (e < EE) {
        int p = atomicAdd(&cursor[dst[e]], 1);
        eidx[p] = src[e];
    }
}

// ================= Weight transpose + bf16 convert =================
__global__ void w_transpose(const float* __restrict__ w, unsigned short* __restrict__ wt) {
    int idx = blockIdx.x * 256 + threadIdx.x;  // n*512 + k, k fastest
    int n = idx >> 9, k = idx & 511;
    wt[idx] = f2b(w[(size_t)k * HH + n]);
}

// ================= Aggregation: bf16 gather, one wave per node =================
__global__ __launch_bounds__(256) void gather_rows_b(
    const unsigned short* __restrict__ xb, const int* __restrict__ start,
    const int* __restrict__ eidx, unsigned short* __restrict__ agg)
{
    int node = blockIdx.x * 4 + (threadIdx.x >> 6);
    if (node >= NN) return;
    int c0 = (threadIdx.x & 63) << 3;   // 8 bf16 per lane
    float a[8] = {0.f,0.f,0.f,0.f,0.f,0.f,0.f,0.f};
    int e1 = start[node + 1];
    for (int e = start[node]; e < e1; ++e) {
        ushort8 v = *(const ushort8*)(xb + (size_t)eidx[e] * HH + c0);
        #pragma unroll
        for (int j = 0; j < 8; ++j) a[j] += b2f(v[j]);
    }
    ushort8 o;
    #pragma unroll
    for (int j = 0; j < 8; ++j) o[j] = f2b(a[j]);
    *(ushort8*)(agg + (size_t)node * HH + c0) = o;
}

// Layer-1 scalar aggregate via CSR
__global__ void gather_scalar(const float* __restrict__ x, const int* __restrict__ start,
                              const int* __restrict__ eidx, float* __restrict__ agg0) {
    int i = blockIdx.x * blockDim.x + threadIdx.x;
    if (i >= NN) return;
    float s = 0.f;
    int e1 = start[i + 1];
    for (int e = start[i]; e < e1; ++e) s += x[eidx[e]];
    agg0[i] = s;
}

// x1[i][h] = relu(agg0[i]*w_rel[h] + b[h] + x[i]*w_root[h]); writes f32 + bf16
__global__ void layer1_expand(const float* __restrict__ x,
                              const float* __restrict__ agg0,
                              const float* __restrict__ w_rel,
                              const float* __restrict__ b,
                              const float* __restrict__ w_root,
                              float* __restrict__ x1,
                              unsigned short* __restrict__ x1b) {
    int idx = blockIdx.x * blockDim.x + threadIdx.x;
    int i = idx >> 7;
    if (i >= NN) return;
    int q = (idx & 127) << 2;
    float a = agg0[i], xv = x[i];
    float4 wr = *(const float4*)&w_rel[q];
    float4 bb = *(const float4*)&b[q];
    float4 wt = *(const float4*)&w_root[q];
    float4 o;
    o.x = fmaxf(fmaf(a, wr.x, fmaf(xv, wt.x, bb.x)), 0.f);
    o.y = fmaxf(fmaf(a, wr.y, fmaf(xv, wt.y, bb.y)), 0.f);
    o.z = fmaxf(fmaf(a, wr.z, fmaf(xv, wt.z, bb.z)), 0.f);
    o.w = fmaxf(fmaf(a, wr.w, fmaf(xv, wt.w, bb.w)), 0.f);
    *(float4*)&x1[(size_t)i * HH + q] = o;
    ushort4 ob = { f2b(o.x), f2b(o.y), f2b(o.z), f2b(o.w) };
    *(ushort4*)&x1b[(size_t)i * HH + q] = ob;
}

// ================= MFMA GEMM =================
// out = (relu?)(AB@WrT^T + XBp@WoT^T + bias) + resid; optionally also writes bf16(out).
// 128x128 tile, BK=32, 4 waves; LDS XOR-swizzled (slot ^= (row>>1)&3) both sides.
__device__ inline void gload16(const void* g, void* l) {
    __builtin_amdgcn_global_load_lds(
        (const __attribute__((address_space(1))) unsigned int*)g,
        (__attribute__((address_space(3))) unsigned int*)l,
        16, 0, 0);
}

template<bool RELU, bool WB16>
__global__ __launch_bounds__(256, 2) void gemm_mfma(
    const unsigned short* __restrict__ AB, const unsigned short* __restrict__ XBp,
    const unsigned short* __restrict__ WrT, const unsigned short* __restrict__ WoT,
    const float* __restrict__ bias, const float* __restrict__ resid,
    float* __restrict__ out, unsigned short* __restrict__ outb)
{
    __shared__ unsigned short As[128 * 32];  // [row][k], k-slots XOR-swizzled
    __shared__ unsigned short Bs[128 * 32];  // [col][k]
    const int tid  = threadIdx.x;
    const int wave = tid >> 6, lane = tid & 63;

    // Bijective XCD-chunked mapping: 3128 blocks = 8 XCDs x 391.
    const int bid = blockIdx.x;
    const int nid = (bid & 7) * 391 + (bid >> 3);
    const int col0 = (nid & 3) << 7;   // n-tile fastest within chunk -> A-panel L2 reuse
    const int row0 = (nid >> 2) << 7;

    const int wr = wave >> 1, wc = wave & 1; // wave's 64x64 quadrant
    const int l16 = lane & 15, lq = lane >> 4;
    const int sRow = lane >> 2;                              // staging row in chunk
    const int sColSwz = (((lane & 3) ^ ((lane >> 3) & 3)) << 3); // swizzled k-slot (shorts)
    const int xorslot = ((lq ^ ((lane >> 1) & 3)) << 3);     // read-side slot (shorts)

    f32x4 acc[4][4];
    #pragma unroll
    for (int m = 0; m < 4; ++m)
        #pragma unroll
        for (int n = 0; n < 4; ++n)
            acc[m][n] = (f32x4){0.f, 0.f, 0.f, 0.f};

    for (int k0 = 0; k0 < 1024; k0 += 32) {
        const unsigned short* Ap = (k0 < 512) ? AB  : XBp;
        const unsigned short* Wp = (k0 < 512) ? WrT : WoT;
        const int kk = k0 & 511;
        #pragma unroll
        for (int i = 0; i < 2; ++i) {
            int chunk = wave * 2 + i;
            int grow = row0 + chunk * 16 + sRow;
            if (grow >= NN) grow = NN - 1;               // clamp: valid reads, stores guarded
            gload16(Ap + (size_t)grow * HH + kk + sColSwz, As + chunk * 512);
            int gcol = col0 + chunk * 16 + sRow;
            gload16(Wp + (size_t)gcol * HH + kk + sColSwz, Bs + chunk * 512);
        }
        __syncthreads();

        short8 af[4], bf[4];
        #pragma unroll
        for (int m = 0; m < 4; ++m)
            af[m] = *(const short8*)(As + (wr * 64 + m * 16 + l16) * 32 + xorslot);
        #pragma unroll
        for (int n = 0; n < 4; ++n)
            bf[n] = *(const short8*)(Bs + (wc * 64 + n * 16 + l16) * 32 + xorslot);
        #pragma unroll
        for (int m = 0; m < 4; ++m)
            #pragma unroll
            for (int n = 0; n < 4; ++n)
                acc[m][n] = __builtin_amdgcn_mfma_f32_16x16x32_bf16(af[m], bf[n], acc[m][n], 0, 0, 0);
        __syncthreads();
    }

    // Epilogue: + bias (+relu) + resid(f32); f32 store (+ optional bf16 store)
    #pragma unroll
    for (int m = 0; m < 4; ++m) {
        #pragma unroll
        for (int j = 0; j < 4; ++j) {
            int row = row0 + wr * 64 + m * 16 + lq * 4 + j;
            if (row >= NN) continue;
            #pragma unroll
            for (int n = 0; n < 4; ++n) {
                int col = col0 + wc * 64 + n * 16 + l16;
                float v = acc[m][n][j] + bias[col];
                if (RELU) v = fmaxf(v, 0.f);
                v += resid[(size_t)row * HH + col];
                out[(size_t)row * HH + col] = v;
                if (WB16) outb[(size_t)row * HH + col] = f2b(v);
            }
        }
    }
}

extern "C" void kernel_launch(void* const* d_in, const int* in_sizes, int n_in,
                              void* d_out, int out_size, void* d_ws, size_t ws_size,
                              hipStream_t stream) {
    const float* x   = (const float*)d_in[0];
    const int*   ei  = (const int*)d_in[1];
    const int*   src = ei;
    const int*   dst = ei + EE;
    const float* w_rel1  = (const float*)d_in[2];
    const float* b_rel1  = (const float*)d_in[3];
    const float* w_root1 = (const float*)d_in[4];
    const float* w_rel2  = (const float*)d_in[5];
    const float* b_rel2  = (const float*)d_in[6];
    const float* w_root2 = (const float*)d_in[7];
    const float* w_rel3  = (const float*)d_in[8];
    const float* b_rel3  = (const float*)d_in[9];
    const float* w_root3 = (const float*)d_in[10];
    const float* w_rel4  = (const float*)d_in[11];
    const float* b_rel4  = (const float*)d_in[12];
    const float* w_root4 = (const float*)d_in[13];

    const size_t NH = (size_t)NN * HH;
    float*          W0   = (float*)d_ws;                 // x1 / x3 (f32)
    unsigned short* XB   = (unsigned short*)(W0 + NH);   // bf16 ping
    unsigned short* XB2  = XB + NH;                      // bf16 pong
    unsigned short* AGB  = XB2 + NH;                     // agg bf16
    unsigned short* WT   = AGB + NH;                     // 6 transposed bf16 weights
    float*          agg0 = (float*)(WT + 6 * 262144);
    int*            csr  = (int*)(agg0 + NN);
    int* deg       = csr;
    int* start     = csr + NN;
    int* cursor    = start + NN + 1;
    int* eidx      = cursor + NN;
    int* blockSums = eidx + EE;
    float* out = (float*)d_out;

    unsigned short* WrT2 = WT;
    unsigned short* WoT2 = WT + 1 * 262144;
    unsigned short* WrT3 = WT + 2 * 262144;
    unsigned short* WoT3 = WT + 3 * 262144;
    unsigned short* WrT4 = WT + 4 * 262144;
    unsigned short* WoT4 = WT + 5 * 262144;

    const int gGemm = 3128;  // 782 m-tiles x 4 n-tiles, XCD-chunked in-kernel

    // ---- CSR build ----
    hipMemsetAsync(deg, 0, NN * sizeof(int), stream);
    histo_deg<<<(EE + 255) / 256, 256, 0, stream>>>(dst, deg);
    scan_reduce<<<NB_SCAN, 256, 0, stream>>>(deg, blockSums);
    scan_top<<<1, 128, 0, stream>>>(blockSums, start);
    scan_down<<<NB_SCAN, 256, 0, stream>>>(deg, blockSums, start, cursor);
    csr_fill<<<(EE + 255) / 256, 256, 0, stream>>>(src, dst, cursor, eidx);

    // ---- Weights -> transposed bf16 ----
    w_transpose<<<1024, 256, 0, stream>>>(w_rel2,  WrT2);
    w_transpose<<<1024, 256, 0, stream>>>(w_root2, WoT2);
    w_transpose<<<1024, 256, 0, stream>>>(w_rel3,  WrT3);
    w_transpose<<<1024, 256, 0, stream>>>(w_root3, WoT3);
    w_transpose<<<1024, 256, 0, stream>>>(w_rel4,  WrT4);
    w_transpose<<<1024, 256, 0, stream>>>(w_root4, WoT4);

    // ---- Layer 1: x1 -> W0 (f32) + XB (bf16) ----
    gather_scalar<<<(NN + 255) / 256, 256, 0, stream>>>(x, start, eidx, agg0);
    layer1_expand<<<50000, 256, 0, stream>>>(x, agg0, w_rel1, b_rel1, w_root1, W0, XB);

    // ---- Layer 2: x2 = relu(conv(x1)) + x1 -> d_out (f32) + XB2 (bf16) ----
    gather_rows_b<<<25000, 256, 0, stream>>>(XB, start, eidx, AGB);
    gemm_mfma<true, true><<<gGemm, 256, 0, stream>>>(AGB, XB, WrT2, WoT2, b_rel2, W0, out, XB2);

    // ---- Layer 3: x3 = conv(x2) + x2 -> W0 (f32) + XB (bf16) ----
    gather_rows_b<<<25000, 256, 0, stream>>>(XB2, start, eidx, AGB);
    gemm_mfma<false, true><<<gGemm, 256, 0, stream>>>(AGB, XB2, WrT3, WoT3, b_rel3, out, W0, XB);

    // ---- Layer 4: x4 = conv(x3) + x3 -> d_out (f32) ----
    gather_rows_b<<<25000, 256, 0, stream>>>(XB, start, eidx, AGB);
    gemm_mfma<false, false><<<gGemm, 256, 0, stream>>>(AGB, XB, WrT4, WoT4, b_rel4, W0, out, nullptr);
}

// Round 5
// 1033.870 us; speedup vs baseline: 11.8461x; 1.0925x over previous
//
#include <hip/hip_runtime.h>

#define NN 100000
#define EE 400000
#define HH 512
#define NB_SCAN 98   // ceil(NN/1024)

typedef __attribute__((ext_vector_type(8))) short short8;
typedef __attribute__((ext_vector_type(8))) unsigned short ushort8;
typedef __attribute__((ext_vector_type(4))) float f32x4;

__device__ inline unsigned short f2b(float f) {   // f32 -> bf16 RNE
    unsigned int u = __float_as_uint(f);
    return (unsigned short)((u + 0x7fffu + ((u >> 16) & 1u)) >> 16);
}
__device__ inline float b2f(unsigned short b) {
    return __uint_as_float(((unsigned int)b) << 16);
}

// ================= CSR build =================
__global__ void histo_deg(const int* __restrict__ dst, int* __restrict__ deg) {
    int e = blockIdx.x * blockDim.x + threadIdx.x;
    if (e < EE) atomicAdd(&deg[dst[e]], 1);
}

__global__ void scan_reduce(const int* __restrict__ deg, int* __restrict__ blockSums) {
    __shared__ int s[256];
    int b = blockIdx.x, t = threadIdx.x;
    int base = b * 1024 + t * 4;
    int v = 0;
    #pragma unroll
    for (int j = 0; j < 4; ++j) { int i = base + j; if (i < NN) v += deg[i]; }
    s[t] = v; __syncthreads();
    for (int off = 128; off > 0; off >>= 1) {
        if (t < off) s[t] += s[t + off];
        __syncthreads();
    }
    if (t == 0) blockSums[b] = s[0];
}

__global__ void scan_top(int* __restrict__ blockSums, int* __restrict__ start) {
    __shared__ int s[128];
    int t = threadIdx.x;
    s[t] = (t < NB_SCAN) ? blockSums[t] : 0;
    __syncthreads();
    for (int off = 1; off < 128; off <<= 1) {
        int u = (t >= off) ? s[t - off] : 0;
        __syncthreads();
        s[t] += u;
        __syncthreads();
    }
    if (t < NB_SCAN) blockSums[t] = (t == 0) ? 0 : s[t - 1];  // exclusive
    if (t == 0) start[NN] = EE;
}

__global__ void scan_down(const int* __restrict__ deg, const int* __restrict__ blockSums,
                          int* __restrict__ start, int* __restrict__ cursor) {
    __shared__ int s[256];
    int b = blockIdx.x, t = threadIdx.x;
    int base = b * 1024 + t * 4;
    int v[4]; int sum = 0;
    #pragma unroll
    for (int j = 0; j < 4; ++j) {
        int i = base + j;
        v[j] = (i < NN) ? deg[i] : 0;
        sum += v[j];
    }
    s[t] = sum; __syncthreads();
    for (int off = 1; off < 256; off <<= 1) {
        int u = (t >= off) ? s[t - off] : 0;
        __syncthreads();
        s[t] += u;
        __syncthreads();
    }
    int excl = blockSums[b] + ((t == 0) ? 0 : s[t - 1]);
    #pragma unroll
    for (int j = 0; j < 4; ++j) {
        int i = base + j;
        if (i < NN) { start[i] = excl; cursor[i] = excl; excl += v[j]; }
    }
}

__global__ void csr_fill(const int* __restrict__ src, const int* __restrict__ dst,
                         int* __restrict__ cursor, int* __restrict__ eidx) {
    int e = blockIdx.x * blockDim.x + threadIdx.x;
    if (e < EE) {
        int p = atomicAdd(&cursor[dst[e]], 1);
        eidx[p] = src[e];
    }
}

// ================= Weight transpose + bf16 convert =================
__global__ void w_transpose(const float* __restrict__ w, unsigned short* __restrict__ wt) {
    int idx = blockIdx.x * 256 + threadIdx.x;  // n*512 + k, k fastest
    int n = idx >> 9, k = idx & 511;
    wt[idx] = f2b(w[(size_t)k * HH + n]);
}

// ================= Aggregation: bf16 gather, one wave per node =================
__global__ __launch_bounds__(256) void gather_rows_b(
    const unsigned short* __restrict__ xb, const int* __restrict__ start,
    const int* __restrict__ eidx, unsigned short* __restrict__ agg)
{
    int node = blockIdx.x * 4 + (threadIdx.x >> 6);
    if (node >= NN) return;
    int c0 = (threadIdx.x & 63) << 3;   // 8 bf16 per lane
    float a[8] = {0.f,0.f,0.f,0.f,0.f,0.f,0.f,0.f};
    int e1 = start[node + 1];
    for (int e = start[node]; e < e1; ++e) {
        ushort8 v = *(const ushort8*)(xb + (size_t)eidx[e] * HH + c0);
        #pragma unroll
        for (int j = 0; j < 8; ++j) a[j] += b2f(v[j]);
    }
    ushort8 o;
    #pragma unroll
    for (int j = 0; j < 8; ++j) o[j] = f2b(a[j]);
    *(ushort8*)(agg + (size_t)node * HH + c0) = o;
}

// Layer-1 scalar aggregate via CSR
__global__ void gather_scalar(const float* __restrict__ x, const int* __restrict__ start,
                              const int* __restrict__ eidx, float* __restrict__ agg0) {
    int i = blockIdx.x * blockDim.x + threadIdx.x;
    if (i >= NN) return;
    float s = 0.f;
    int e1 = start[i + 1];
    for (int e = start[i]; e < e1; ++e) s += x[eidx[e]];
    agg0[i] = s;
}

// x1[i][h] = relu(agg0[i]*w_rel[h] + b[h] + x[i]*w_root[h]); writes f32 + bf16
__global__ void layer1_expand(const float* __restrict__ x,
                              const float* __restrict__ agg0,
                              const float* __restrict__ w_rel,
                              const float* __restrict__ b,
                              const float* __restrict__ w_root,
                              float* __restrict__ x1,
                              unsigned short* __restrict__ x1b) {
    int idx = blockIdx.x * blockDim.x + threadIdx.x;
    int i = idx >> 7;
    if (i >= NN) return;
    int q = (idx & 127) << 2;
    float a = agg0[i], xv = x[i];
    float4 wr = *(const float4*)&w_rel[q];
    float4 bb = *(const float4*)&b[q];
    float4 wt = *(const float4*)&w_root[q];
    float4 o;
    o.x = fmaxf(fmaf(a, wr.x, fmaf(xv, wt.x, bb.x)), 0.f);
    o.y = fmaxf(fmaf(a, wr.y, fmaf(xv, wt.y, bb.y)), 0.f);
    o.z = fmaxf(fmaf(a, wr.z, fmaf(xv, wt.z, bb.z)), 0.f);
    o.w = fmaxf(fmaf(a, wr.w, fmaf(xv, wt.w, bb.w)), 0.f);
    *(float4*)&x1[(size_t)i * HH + q] = o;
    ushort4 ob = { f2b(o.x), f2b(o.y), f2b(o.z), f2b(o.w) };
    *(ushort4*)&x1b[(size_t)i * HH + q] = ob;
}

// ================= MFMA GEMM =================
// out = (relu?)(AB@WrT^T + XBp@WoT^T + bias) + resid
// 128x128 tile, BK=32, 4 waves, double-buffered LDS (stage t+1 before compute t,
// ONE barrier per K-step). LDS k-slots XOR-swizzled both sides.
__device__ inline void gload16(const void* g, void* l) {
    __builtin_amdgcn_global_load_lds(
        (const __attribute__((address_space(1))) unsigned int*)g,
        (__attribute__((address_space(3))) unsigned int*)l,
        16, 0, 0);
}

template<bool RELU, bool RB16, bool WF32, bool WB16>
__global__ __launch_bounds__(256, 2) void gemm_mfma(
    const unsigned short* __restrict__ AB, const unsigned short* __restrict__ XBp,
    const unsigned short* __restrict__ WrT, const unsigned short* __restrict__ WoT,
    const float* __restrict__ bias, const void* __restrict__ residv,
    float* __restrict__ out, unsigned short* __restrict__ outb)
{
    __shared__ unsigned short As[2 * 128 * 32];  // [buf][row][k], k-slots swizzled
    __shared__ unsigned short Bs[2 * 128 * 32];  // [buf][col][k]
    const int tid  = threadIdx.x;
    const int wave = tid >> 6, lane = tid & 63;

    // Bijective XCD-chunked mapping: 3128 blocks = 8 XCDs x 391.
    const int bid = blockIdx.x;
    const int nid = (bid & 7) * 391 + (bid >> 3);
    const int col0 = (nid & 3) << 7;   // n-tile fastest within chunk -> A-panel L2 reuse
    const int row0 = (nid >> 2) << 7;

    const int wr = wave >> 1, wc = wave & 1; // wave's 64x64 quadrant
    const int l16 = lane & 15, lq = lane >> 4;
    const int sRow = lane >> 2;                                  // staging row in chunk
    const int sColSwz = (((lane & 3) ^ ((lane >> 3) & 3)) << 3); // swizzled k-slot (shorts)
    const int xorslot = ((lq ^ ((lane >> 1) & 3)) << 3);         // read-side slot (shorts)

    // Precompute staged global rows/cols (clamped; stores guarded)
    int rowA[2], colB[2];
    #pragma unroll
    for (int i = 0; i < 2; ++i) {
        int chunk = (wave << 1) + i;
        int gr = row0 + chunk * 16 + sRow;
        rowA[i] = (gr >= NN) ? (NN - 1) : gr;
        colB[i] = col0 + chunk * 16 + sRow;
    }

    f32x4 acc[4][4];
    #pragma unroll
    for (int m = 0; m < 4; ++m)
        #pragma unroll
        for (int n = 0; n < 4; ++n)
            acc[m][n] = (f32x4){0.f, 0.f, 0.f, 0.f};

    auto STAGE = [&](unsigned short* Asb, unsigned short* Bsb, int t) {
        const int k0 = t << 5;
        const unsigned short* Ap = (k0 < 512) ? AB  : XBp;
        const unsigned short* Wp = (k0 < 512) ? WrT : WoT;
        const int kk = k0 & 511;
        #pragma unroll
        for (int i = 0; i < 2; ++i) {
            int chunk = (wave << 1) + i;
            gload16(Ap + (size_t)rowA[i] * HH + kk + sColSwz, Asb + chunk * 512);
            gload16(Wp + (size_t)colB[i] * HH + kk + sColSwz, Bsb + chunk * 512);
        }
    };

    auto COMPUTE = [&](const unsigned short* Asb, const unsigned short* Bsb) {
        short8 af[4], bfv[4];
        #pragma unroll
        for (int m = 0; m < 4; ++m)
            af[m] = *(const short8*)(Asb + (wr * 64 + m * 16 + l16) * 32 + xorslot);
        #pragma unroll
        for (int n = 0; n < 4; ++n)
            bfv[n] = *(const short8*)(Bsb + (wc * 64 + n * 16 + l16) * 32 + xorslot);
        #pragma unroll
        for (int m = 0; m < 4; ++m)
            #pragma unroll
            for (int n = 0; n < 4; ++n)
                acc[m][n] = __builtin_amdgcn_mfma_f32_16x16x32_bf16(af[m], bfv[n], acc[m][n], 0, 0, 0);
    };

    unsigned short* A0 = As;        unsigned short* A1 = As + 4096;
    unsigned short* B0 = Bs;        unsigned short* B1 = Bs + 4096;

    STAGE(A0, B0, 0);
    __syncthreads();                       // drains vmcnt(0): tile 0 resident
    for (int t = 0; t < 32; t += 2) {
        STAGE(A1, B1, t + 1);              // prefetch next tile (hidden under compute)
        COMPUTE(A0, B0);
        __syncthreads();                   // next staged + everyone done with buf0
        if (t + 2 < 32) STAGE(A0, B0, t + 2);
        COMPUTE(A1, B1);
        __syncthreads();
    }

    // Epilogue: + bias (+relu) + resid; optional f32 / bf16 stores
    const float*          residf = (const float*)residv;
    const unsigned short* residb = (const unsigned short*)residv;
    float bias_n[4];
    #pragma unroll
    for (int n = 0; n < 4; ++n) bias_n[n] = bias[col0 + wc * 64 + n * 16 + l16];

    #pragma unroll
    for (int m = 0; m < 4; ++m) {
        #pragma unroll
        for (int j = 0; j < 4; ++j) {
            int row = row0 + wr * 64 + m * 16 + lq * 4 + j;
            if (row >= NN) continue;
            #pragma unroll
            for (int n = 0; n < 4; ++n) {
                int col = col0 + wc * 64 + n * 16 + l16;
                size_t off = (size_t)row * HH + col;
                float v = acc[m][n][j] + bias_n[n];
                if (RELU) v = fmaxf(v, 0.f);
                v += RB16 ? b2f(residb[off]) : residf[off];
                if (WF32) out[off] = v;
                if (WB16) outb[off] = f2b(v);
            }
        }
    }
}

extern "C" void kernel_launch(void* const* d_in, const int* in_sizes, int n_in,
                              void* d_out, int out_size, void* d_ws, size_t ws_size,
                              hipStream_t stream) {
    const float* x   = (const float*)d_in[0];
    const int*   ei  = (const int*)d_in[1];
    const int*   src = ei;
    const int*   dst = ei + EE;
    const float* w_rel1  = (const float*)d_in[2];
    const float* b_rel1  = (const float*)d_in[3];
    const float* w_root1 = (const float*)d_in[4];
    const float* w_rel2  = (const float*)d_in[5];
    const float* b_rel2  = (const float*)d_in[6];
    const float* w_root2 = (const float*)d_in[7];
    const float* w_rel3  = (const float*)d_in[8];
    const float* b_rel3  = (const float*)d_in[9];
    const float* w_root3 = (const float*)d_in[10];
    const float* w_rel4  = (const float*)d_in[11];
    const float* b_rel4  = (const float*)d_in[12];
    const float* w_root4 = (const float*)d_in[13];

    const size_t NH = (size_t)NN * HH;
    float*          W0   = (float*)d_ws;                 // x1 (f32), then x3 (f32)
    unsigned short* XB   = (unsigned short*)(W0 + NH);   // bf16 ping (x1, then x3)
    unsigned short* XB2  = XB + NH;                      // bf16 pong (x2)
    unsigned short* AGB  = XB2 + NH;                     // agg bf16
    unsigned short* WT   = AGB + NH;                     // 6 transposed bf16 weights
    float*          agg0 = (float*)(WT + 6 * 262144);
    int*            csr  = (int*)(agg0 + NN);
    int* deg       = csr;
    int* start     = csr + NN;
    int* cursor    = start + NN + 1;
    int* eidx      = cursor + NN;
    int* blockSums = eidx + EE;
    float* out = (float*)d_out;

    unsigned short* WrT2 = WT;
    unsigned short* WoT2 = WT + 1 * 262144;
    unsigned short* WrT3 = WT + 2 * 262144;
    unsigned short* WoT3 = WT + 3 * 262144;
    unsigned short* WrT4 = WT + 4 * 262144;
    unsigned short* WoT4 = WT + 5 * 262144;

    const int gGemm = 3128;  // 782 m-tiles x 4 n-tiles, XCD-chunked in-kernel

    // ---- CSR build ----
    hipMemsetAsync(deg, 0, NN * sizeof(int), stream);
    histo_deg<<<(EE + 255) / 256, 256, 0, stream>>>(dst, deg);
    scan_reduce<<<NB_SCAN, 256, 0, stream>>>(deg, blockSums);
    scan_top<<<1, 128, 0, stream>>>(blockSums, start);
    scan_down<<<NB_SCAN, 256, 0, stream>>>(deg, blockSums, start, cursor);
    csr_fill<<<(EE + 255) / 256, 256, 0, stream>>>(src, dst, cursor, eidx);

    // ---- Weights -> transposed bf16 ----
    w_transpose<<<1024, 256, 0, stream>>>(w_rel2,  WrT2);
    w_transpose<<<1024, 256, 0, stream>>>(w_root2, WoT2);
    w_transpose<<<1024, 256, 0, stream>>>(w_rel3,  WrT3);
    w_transpose<<<1024, 256, 0, stream>>>(w_root3, WoT3);
    w_transpose<<<1024, 256, 0, stream>>>(w_rel4,  WrT4);
    w_transpose<<<1024, 256, 0, stream>>>(w_root4, WoT4);

    // ---- Layer 1: x1 -> W0 (f32) + XB (bf16) ----
    gather_scalar<<<(NN + 255) / 256, 256, 0, stream>>>(x, start, eidx, agg0);
    layer1_expand<<<50000, 256, 0, stream>>>(x, agg0, w_rel1, b_rel1, w_root1, W0, XB);

    // ---- Layer 2: x2 = relu(conv(x1)) + x1 -> XB2 (bf16 only) ----
    gather_rows_b<<<25000, 256, 0, stream>>>(XB, start, eidx, AGB);
    gemm_mfma<true, false, false, true><<<gGemm, 256, 0, stream>>>(
        AGB, XB, WrT2, WoT2, b_rel2, W0, nullptr, XB2);

    // ---- Layer 3: x3 = conv(x2) + x2 -> W0 (f32) + XB (bf16); resid = bf16 x2 ----
    gather_rows_b<<<25000, 256, 0, stream>>>(XB2, start, eidx, AGB);
    gemm_mfma<false, true, true, true><<<gGemm, 256, 0, stream>>>(
        AGB, XB2, WrT3, WoT3, b_rel3, XB2, W0, XB);

    // ---- Layer 4: x4 = conv(x3) + x3 -> d_out (f32); resid = f32 x3 ----
    gather_rows_b<<<25000, 256, 0, stream>>>(XB, start, eidx, AGB);
    gemm_mfma<false, false, true, false><<<gGemm, 256, 0, stream>>>(
        AGB, XB, WrT4, WoT4, b_rel4, W0, out, nullptr);
}